// Round 3
// baseline (709.335 us; speedup 1.0000x reference)
//
#include <hip/hip_runtime.h>
#include <hip/hip_bf16.h>

#define D 128
#define KTERMS 16

// ---------- W transpose: WT[k*D+c] = W[c*D+k] ----------
__global__ __launch_bounds__(256) void transpose_w(const float* __restrict__ W,
                                                   float* __restrict__ WT) {
    int idx = blockIdx.x * 256 + threadIdx.x;
    if (idx < D * D) {
        int c = idx >> 7, k = idx & 127;
        WT[k * D + c] = W[c * D + k];
    }
}

// ---------- degree histogram ----------
__global__ __launch_bounds__(256) void deg_kernel(const int* __restrict__ dst,
                                                  float* __restrict__ deg, int E) {
    int e = blockIdx.x * 256 + threadIdx.x;
    if (e < E) atomicAdd(&deg[dst[e]], 1.0f);
}

__global__ __launch_bounds__(256) void invdeg_kernel(const float* __restrict__ deg,
                                                     float* __restrict__ invdeg, int N) {
    int i = blockIdx.x * 256 + threadIdx.x;
    if (i < N) invdeg[i] = 1.0f / fmaxf(deg[i], 1.0f);
}

// ---------- edge scatter-add: one wave per edge, 2 floats per lane ----------
__global__ __launch_bounds__(256) void scatter_kernel(const float* __restrict__ xin,
                                                      const int* __restrict__ src,
                                                      const int* __restrict__ dst,
                                                      float* __restrict__ agg, int E) {
    int idx = blockIdx.x * 256 + threadIdx.x;
    int e = idx >> 6, lane = idx & 63;
    if (e >= E) return;
    int s = src[e], t = dst[e];
    const float2 v = *reinterpret_cast<const float2*>(&xin[(size_t)s * D + lane * 2]);
    atomicAdd(&agg[(size_t)t * D + lane * 2], v.x);
    atomicAdd(&agg[(size_t)t * D + lane * 2 + 1], v.y);
}

// ---------- fused SAGE layer: out = [relu](invdeg[r]*(agg@WlT) + x@WrT + b) ----------
__global__ __launch_bounds__(256) void sage_kernel(const float* __restrict__ agg,
                                                   const float* __restrict__ xin,
                                                   const float* __restrict__ WlT,
                                                   const float* __restrict__ WrT,
                                                   const float* __restrict__ bias,
                                                   const float* __restrict__ invdeg,
                                                   float* __restrict__ out, int relu) {
    int c = threadIdx.x & 127;
    int half = threadIdx.x >> 7;
    int r0 = blockIdx.x * 16 + half * 8;
    float acc1[8], acc2[8];
#pragma unroll
    for (int i = 0; i < 8; i++) { acc1[i] = 0.0f; acc2[i] = 0.0f; }
    for (int k = 0; k < D; k += 4) {
        float wl0 = WlT[(k + 0) * D + c];
        float wl1 = WlT[(k + 1) * D + c];
        float wl2 = WlT[(k + 2) * D + c];
        float wl3 = WlT[(k + 3) * D + c];
        float wr0 = WrT[(k + 0) * D + c];
        float wr1 = WrT[(k + 1) * D + c];
        float wr2 = WrT[(k + 2) * D + c];
        float wr3 = WrT[(k + 3) * D + c];
#pragma unroll
        for (int i = 0; i < 8; i++) {
            const float4 a  = *reinterpret_cast<const float4*>(&agg[(size_t)(r0 + i) * D + k]);
            const float4 xv = *reinterpret_cast<const float4*>(&xin[(size_t)(r0 + i) * D + k]);
            acc1[i] += a.x * wl0 + a.y * wl1 + a.z * wl2 + a.w * wl3;
            acc2[i] += xv.x * wr0 + xv.y * wr1 + xv.z * wr2 + xv.w * wr3;
        }
    }
    float b = bias[c];
#pragma unroll
    for (int i = 0; i < 8; i++) {
        int r = r0 + i;
        float v = invdeg[r] * acc1[i] + acc2[i] + b;
        if (relu) v = fmaxf(v, 0.0f);
        out[(size_t)r * D + c] = v;
    }
}

// ---------- per-node cosine score vs aux, and w = exp(-s^2) ----------
__global__ __launch_bounds__(256) void score_kernel(const float* __restrict__ h,
                                                    const float* __restrict__ aux,
                                                    float* __restrict__ sbuf,
                                                    float* __restrict__ wbuf, int N) {
    int wave = threadIdx.x >> 6, lane = threadIdx.x & 63;
    int node = blockIdx.x * 4 + wave;
    if (node >= N) return;
    float2 hv = *reinterpret_cast<const float2*>(&h[(size_t)node * D + lane * 2]);
    float2 av = *reinterpret_cast<const float2*>(&aux[lane * 2]);
    float dot = hv.x * av.x + hv.y * av.y;
    float nh = hv.x * hv.x + hv.y * hv.y;
    float na = av.x * av.x + av.y * av.y;
    for (int m = 1; m < 64; m <<= 1) {
        dot += __shfl_xor(dot, m);
        nh += __shfl_xor(nh, m);
        na += __shfl_xor(na, m);
    }
    if (lane == 0) {
        float hn = fmaxf(sqrtf(nh), 1e-8f);
        float an = fmaxf(sqrtf(na), 1e-8f);
        float sc = dot / (hn * an);
        sbuf[node] = sc;
        wbuf[node] = expf(-sc * sc);
    }
}

// ---------- moments: M_k[d] = sum_j w_j s_j^k h[j][d];  m_k = sum_j w_j s_j^k ----------
__global__ __launch_bounds__(128) void moments_kernel(const float* __restrict__ h,
                                                      const float* __restrict__ sbuf,
                                                      const float* __restrict__ wbuf,
                                                      float* __restrict__ M,
                                                      float* __restrict__ mden, int N) {
    int tid = threadIdx.x;
    int j0 = blockIdx.x * 64;
    float acc[KTERMS], macc[KTERMS];
#pragma unroll
    for (int k = 0; k < KTERMS; k++) { acc[k] = 0.0f; macc[k] = 0.0f; }
    for (int j = j0; j < j0 + 64; j++) {
        float sj = sbuf[j];
        float wj = wbuf[j];
        float hv = h[(size_t)j * D + tid];
        float coef = wj;
#pragma unroll
        for (int k = 0; k < KTERMS; k++) {
            acc[k] += coef * hv;
            macc[k] += coef;
            coef *= sj;
        }
    }
#pragma unroll
    for (int k = 0; k < KTERMS; k++) atomicAdd(&M[k * D + tid], acc[k]);
    if (tid == 0) {
#pragma unroll
        for (int k = 0; k < KTERMS; k++) atomicAdd(&mden[k], macc[k]);
    }
}

// ---------- z_i = (sum_k a_k s_i^k M_k) / (sum_k a_k s_i^k m_k) ----------
__global__ __launch_bounds__(128) void zcalc_kernel(const float* __restrict__ M,
                                                    const float* __restrict__ mden,
                                                    const float* __restrict__ sbuf,
                                                    float* __restrict__ z, int N) {
    // a_k = 2^k / k!
    const float A[KTERMS] = {1.0f, 2.0f, 2.0f, 1.3333334f, 0.6666667f, 0.26666668f,
                             0.08888889f, 0.025396826f, 0.0063492064f, 0.0014109347f,
                             2.8218695e-4f, 5.1306718e-5f, 8.5511196e-6f, 1.3155569e-6f,
                             1.8793670e-7f, 2.5058226e-8f};
    __shared__ float Ml[KTERMS * D];
    __shared__ float ml[KTERMS];
    int tid = threadIdx.x;
#pragma unroll
    for (int k = 0; k < KTERMS; k++) Ml[k * D + tid] = M[k * D + tid];
    if (tid < KTERMS) ml[tid] = mden[tid];
    __syncthreads();
    int n0 = blockIdx.x * 16;
    for (int n = n0; n < n0 + 16; n++) {
        float si = sbuf[n];
        float num = 0.0f, den = 0.0f, p = 1.0f;
#pragma unroll
        for (int k = 0; k < KTERMS; k++) {
            float ck = A[k] * p;
            num += ck * Ml[k * D + tid];
            den += ck * ml[k];
            p *= si;
        }
        z[(size_t)n * D + tid] = num / den;
    }
}

// ---------- classifier: out[i][c] = [h,z] @ Wc^T + bc, f32 output ----------
__global__ __launch_bounds__(256) void cls_kernel(const float* __restrict__ h,
                                                  const float* __restrict__ z,
                                                  const float* __restrict__ Wc,
                                                  const float* __restrict__ bc,
                                                  float* __restrict__ out, int N) {
    int idx = blockIdx.x * 256 + threadIdx.x;
    int i = idx >> 4, c = idx & 15;
    if (i >= N || c >= 10) return;
    float acc = bc[c];
    const float4* hp = reinterpret_cast<const float4*>(&h[(size_t)i * D]);
    const float4* zp = reinterpret_cast<const float4*>(&z[(size_t)i * D]);
    const float4* w1 = reinterpret_cast<const float4*>(&Wc[(size_t)c * 256]);
    const float4* w2 = reinterpret_cast<const float4*>(&Wc[(size_t)c * 256 + 128]);
#pragma unroll 8
    for (int q = 0; q < 32; q++) {
        float4 a = hp[q], b = w1[q];
        acc += a.x * b.x + a.y * b.y + a.z * b.z + a.w * b.w;
    }
#pragma unroll 8
    for (int q = 0; q < 32; q++) {
        float4 a = zp[q], b = w2[q];
        acc += a.x * b.x + a.y * b.y + a.z * b.z + a.w * b.w;
    }
    out[(size_t)i * 10 + c] = acc;
}

extern "C" void kernel_launch(void* const* d_in, const int* in_sizes, int n_in,
                              void* d_out, int out_size, void* d_ws, size_t ws_size,
                              hipStream_t stream) {
    const float* x   = (const float*)d_in[0];
    const int*   ei  = (const int*)d_in[1];
    const float* W1l = (const float*)d_in[2];
    const float* b1l = (const float*)d_in[3];
    const float* W1r = (const float*)d_in[4];
    const float* W2l = (const float*)d_in[5];
    const float* b2l = (const float*)d_in[6];
    const float* W2r = (const float*)d_in[7];
    const float* aux = (const float*)d_in[8];
    const float* Wc  = (const float*)d_in[9];
    const float* bc  = (const float*)d_in[10];
    float* out = (float*)d_out;

    const int N = in_sizes[0] / D;
    const int E = in_sizes[1] / 2;
    const int* srcArr = ei;
    const int* dstArr = ei + E;

    float* p = (float*)d_ws;
    float* deg    = p; p += N;
    float* invdeg = p; p += N;
    float* sbuf   = p; p += N;
    float* wbuf   = p; p += N;
    float* M      = p; p += KTERMS * D;
    float* mden   = p; p += KTERMS;
    float* WT     = p; p += 4 * D * D;
    float* agg    = p; p += (size_t)N * D;
    float* h1     = p; p += (size_t)N * D;
    float* h2     = p; p += (size_t)N * D;
    float* zb     = p; p += (size_t)N * D;

    // zero accumulators: deg, invdeg, sbuf, wbuf, M, mden (contiguous)
    hipMemsetAsync(deg, 0, (size_t)(4 * N + KTERMS * D + KTERMS) * sizeof(float), stream);

    transpose_w<<<64, 256, 0, stream>>>(W1l, WT + 0 * D * D);
    transpose_w<<<64, 256, 0, stream>>>(W1r, WT + 1 * D * D);
    transpose_w<<<64, 256, 0, stream>>>(W2l, WT + 2 * D * D);
    transpose_w<<<64, 256, 0, stream>>>(W2r, WT + 3 * D * D);

    deg_kernel<<<(E + 255) / 256, 256, 0, stream>>>(dstArr, deg, E);
    invdeg_kernel<<<(N + 255) / 256, 256, 0, stream>>>(deg, invdeg, N);

    // layer 1
    hipMemsetAsync(agg, 0, (size_t)N * D * sizeof(float), stream);
    scatter_kernel<<<E / 4, 256, 0, stream>>>(x, srcArr, dstArr, agg, E);
    sage_kernel<<<N / 16, 256, 0, stream>>>(agg, x, WT + 0 * D * D, WT + 1 * D * D,
                                            b1l, invdeg, h1, 1);
    // layer 2
    hipMemsetAsync(agg, 0, (size_t)N * D * sizeof(float), stream);
    scatter_kernel<<<E / 4, 256, 0, stream>>>(h1, srcArr, dstArr, agg, E);
    sage_kernel<<<N / 16, 256, 0, stream>>>(agg, h1, WT + 2 * D * D, WT + 3 * D * D,
                                            b2l, invdeg, h2, 0);

    // kernel aggregate via Taylor moment expansion
    score_kernel<<<(N + 3) / 4, 256, 0, stream>>>(h2, aux, sbuf, wbuf, N);
    moments_kernel<<<N / 64, 128, 0, stream>>>(h2, sbuf, wbuf, M, mden, N);
    zcalc_kernel<<<N / 16, 128, 0, stream>>>(M, mden, sbuf, zb, N);

    // classifier
    cls_kernel<<<(N * 16) / 256, 256, 0, stream>>>(h2, zb, Wc, bc, out, N);
}

// Round 4
// 347.407 us; speedup vs baseline: 2.0418x; 2.0418x over previous
//
#include <hip/hip_runtime.h>
#include <hip/hip_bf16.h>

#define D 128
#define KTERMS 16

// ---------- W transpose: WT[k*D+c] = W[c*D+k] ----------
__global__ __launch_bounds__(256) void transpose_w(const float* __restrict__ W,
                                                   float* __restrict__ WT) {
    int idx = blockIdx.x * 256 + threadIdx.x;
    if (idx < D * D) {
        int c = idx >> 7, k = idx & 127;
        WT[k * D + c] = W[c * D + k];
    }
}

// ---------- int degree histogram ----------
__global__ __launch_bounds__(256) void degi_kernel(const int* __restrict__ dst,
                                                   int* __restrict__ degi, int E) {
    int e = blockIdx.x * 256 + threadIdx.x;
    if (e < E) atomicAdd(&degi[dst[e]], 1);
}

__global__ __launch_bounds__(256) void invdeg_kernel(const int* __restrict__ degi,
                                                     float* __restrict__ invdeg, int N) {
    int i = blockIdx.x * 256 + threadIdx.x;
    if (i < N) invdeg[i] = 1.0f / fmaxf((float)degi[i], 1.0f);
}

// ---------- exclusive prefix scan of degi -> rowptr (N=16384, 1 block of 1024) ----------
__global__ __launch_bounds__(1024) void scan_kernel(const int* __restrict__ degi,
                                                    int* __restrict__ rowptr, int N) {
    __shared__ int part[1024];
    int tid = threadIdx.x;
    int base = tid * 16;
    int loc[16];
    int s = 0;
#pragma unroll
    for (int i = 0; i < 16; i++) { loc[i] = s; s += degi[base + i]; }
    part[tid] = s;
    __syncthreads();
    for (int off = 1; off < 1024; off <<= 1) {
        int t = (tid >= off) ? part[tid - off] : 0;
        __syncthreads();
        if (tid >= off) part[tid] += t;
        __syncthreads();
    }
    int prefix = part[tid] - s;  // exclusive
#pragma unroll
    for (int i = 0; i < 16; i++) rowptr[base + i] = prefix + loc[i];
    if (tid == 1023) rowptr[N] = prefix + s;
}

// ---------- CSR fill: csr_src[slot] = src of edge, sorted by dst ----------
__global__ __launch_bounds__(256) void fill_kernel(const int* __restrict__ src,
                                                   const int* __restrict__ dst,
                                                   const int* __restrict__ rowptr,
                                                   int* __restrict__ cursor,
                                                   int* __restrict__ csr_src, int E) {
    int e = blockIdx.x * 256 + threadIdx.x;
    if (e < E) {
        int d = dst[e];
        int pos = atomicAdd(&cursor[d], 1);
        csr_src[rowptr[d] + pos] = src[e];
    }
}

// ---------- gather-mean: agg[i] = mean_{j in N(i)} x[j]  (one wave per node) ----------
__global__ __launch_bounds__(256) void gather_kernel(const float* __restrict__ xin,
                                                     const int* __restrict__ rowptr,
                                                     const int* __restrict__ csr_src,
                                                     const float* __restrict__ invdeg,
                                                     float* __restrict__ agg, int N) {
    int wave = threadIdx.x >> 6, lane = threadIdx.x & 63;
    int node = blockIdx.x * 4 + wave;
    if (node >= N) return;
    int beg = rowptr[node], end = rowptr[node + 1];
    float ax = 0.0f, ay = 0.0f;
    for (int j = beg; j < end; j++) {
        int s = csr_src[j];
        const float2 v = *reinterpret_cast<const float2*>(&xin[(size_t)s * D + lane * 2]);
        ax += v.x; ay += v.y;
    }
    float inv = invdeg[node];
    float2 o; o.x = ax * inv; o.y = ay * inv;
    *reinterpret_cast<float2*>(&agg[(size_t)node * D + lane * 2]) = o;
}

// ---------- fused SAGE layer: out = [relu](agg@WlT + x@WrT + b)  (agg pre-normalized) ----------
__global__ __launch_bounds__(256) void sage_kernel(const float* __restrict__ agg,
                                                   const float* __restrict__ xin,
                                                   const float* __restrict__ WlT,
                                                   const float* __restrict__ WrT,
                                                   const float* __restrict__ bias,
                                                   float* __restrict__ out, int relu) {
    int c = threadIdx.x & 127;
    int half = threadIdx.x >> 7;
    int r0 = blockIdx.x * 16 + half * 8;
    float acc1[8], acc2[8];
#pragma unroll
    for (int i = 0; i < 8; i++) { acc1[i] = 0.0f; acc2[i] = 0.0f; }
    for (int k = 0; k < D; k += 4) {
        float wl0 = WlT[(k + 0) * D + c];
        float wl1 = WlT[(k + 1) * D + c];
        float wl2 = WlT[(k + 2) * D + c];
        float wl3 = WlT[(k + 3) * D + c];
        float wr0 = WrT[(k + 0) * D + c];
        float wr1 = WrT[(k + 1) * D + c];
        float wr2 = WrT[(k + 2) * D + c];
        float wr3 = WrT[(k + 3) * D + c];
#pragma unroll
        for (int i = 0; i < 8; i++) {
            const float4 a  = *reinterpret_cast<const float4*>(&agg[(size_t)(r0 + i) * D + k]);
            const float4 xv = *reinterpret_cast<const float4*>(&xin[(size_t)(r0 + i) * D + k]);
            acc1[i] += a.x * wl0 + a.y * wl1 + a.z * wl2 + a.w * wl3;
            acc2[i] += xv.x * wr0 + xv.y * wr1 + xv.z * wr2 + xv.w * wr3;
        }
    }
    float b = bias[c];
#pragma unroll
    for (int i = 0; i < 8; i++) {
        int r = r0 + i;
        float v = acc1[i] + acc2[i] + b;
        if (relu) v = fmaxf(v, 0.0f);
        out[(size_t)r * D + c] = v;
    }
}

// ---------- per-node cosine score vs aux, and w = exp(-s^2) ----------
__global__ __launch_bounds__(256) void score_kernel(const float* __restrict__ h,
                                                    const float* __restrict__ aux,
                                                    float* __restrict__ sbuf,
                                                    float* __restrict__ wbuf, int N) {
    int wave = threadIdx.x >> 6, lane = threadIdx.x & 63;
    int node = blockIdx.x * 4 + wave;
    if (node >= N) return;
    float2 hv = *reinterpret_cast<const float2*>(&h[(size_t)node * D + lane * 2]);
    float2 av = *reinterpret_cast<const float2*>(&aux[lane * 2]);
    float dot = hv.x * av.x + hv.y * av.y;
    float nh = hv.x * hv.x + hv.y * hv.y;
    float na = av.x * av.x + av.y * av.y;
    for (int m = 1; m < 64; m <<= 1) {
        dot += __shfl_xor(dot, m);
        nh += __shfl_xor(nh, m);
        na += __shfl_xor(na, m);
    }
    if (lane == 0) {
        float hn = fmaxf(sqrtf(nh), 1e-8f);
        float an = fmaxf(sqrtf(na), 1e-8f);
        float sc = dot / (hn * an);
        sbuf[node] = sc;
        wbuf[node] = expf(-sc * sc);
    }
}

// ---------- moments: M_k[d] = sum_j w_j s_j^k h[j][d];  m_k = sum_j w_j s_j^k ----------
__global__ __launch_bounds__(128) void moments_kernel(const float* __restrict__ h,
                                                      const float* __restrict__ sbuf,
                                                      const float* __restrict__ wbuf,
                                                      float* __restrict__ M,
                                                      float* __restrict__ mden, int N) {
    int tid = threadIdx.x;
    int j0 = blockIdx.x * 64;
    float acc[KTERMS], macc[KTERMS];
#pragma unroll
    for (int k = 0; k < KTERMS; k++) { acc[k] = 0.0f; macc[k] = 0.0f; }
    for (int j = j0; j < j0 + 64; j++) {
        float sj = sbuf[j];
        float wj = wbuf[j];
        float hv = h[(size_t)j * D + tid];
        float coef = wj;
#pragma unroll
        for (int k = 0; k < KTERMS; k++) {
            acc[k] += coef * hv;
            macc[k] += coef;
            coef *= sj;
        }
    }
#pragma unroll
    for (int k = 0; k < KTERMS; k++) atomicAdd(&M[k * D + tid], acc[k]);
    if (tid == 0) {
#pragma unroll
        for (int k = 0; k < KTERMS; k++) atomicAdd(&mden[k], macc[k]);
    }
}

// ---------- z_i = (sum_k a_k s_i^k M_k) / (sum_k a_k s_i^k m_k) ----------
__global__ __launch_bounds__(128) void zcalc_kernel(const float* __restrict__ M,
                                                    const float* __restrict__ mden,
                                                    const float* __restrict__ sbuf,
                                                    float* __restrict__ z, int N) {
    // a_k = 2^k / k!
    const float A[KTERMS] = {1.0f, 2.0f, 2.0f, 1.3333334f, 0.6666667f, 0.26666668f,
                             0.08888889f, 0.025396826f, 0.0063492064f, 0.0014109347f,
                             2.8218695e-4f, 5.1306718e-5f, 8.5511196e-6f, 1.3155569e-6f,
                             1.8793670e-7f, 2.5058226e-8f};
    __shared__ float Ml[KTERMS * D];
    __shared__ float ml[KTERMS];
    int tid = threadIdx.x;
#pragma unroll
    for (int k = 0; k < KTERMS; k++) Ml[k * D + tid] = M[k * D + tid];
    if (tid < KTERMS) ml[tid] = mden[tid];
    __syncthreads();
    int n0 = blockIdx.x * 16;
    for (int n = n0; n < n0 + 16; n++) {
        float si = sbuf[n];
        float num = 0.0f, den = 0.0f, p = 1.0f;
#pragma unroll
        for (int k = 0; k < KTERMS; k++) {
            float ck = A[k] * p;
            num += ck * Ml[k * D + tid];
            den += ck * ml[k];
            p *= si;
        }
        z[(size_t)n * D + tid] = num / den;
    }
}

// ---------- classifier: out[i][c] = [h,z] @ Wc^T + bc, f32 output ----------
__global__ __launch_bounds__(256) void cls_kernel(const float* __restrict__ h,
                                                  const float* __restrict__ z,
                                                  const float* __restrict__ Wc,
                                                  const float* __restrict__ bc,
                                                  float* __restrict__ out, int N) {
    int idx = blockIdx.x * 256 + threadIdx.x;
    int i = idx >> 4, c = idx & 15;
    if (i >= N || c >= 10) return;
    float acc = bc[c];
    const float4* hp = reinterpret_cast<const float4*>(&h[(size_t)i * D]);
    const float4* zp = reinterpret_cast<const float4*>(&z[(size_t)i * D]);
    const float4* w1 = reinterpret_cast<const float4*>(&Wc[(size_t)c * 256]);
    const float4* w2 = reinterpret_cast<const float4*>(&Wc[(size_t)c * 256 + 128]);
#pragma unroll 8
    for (int q = 0; q < 32; q++) {
        float4 a = hp[q], b = w1[q];
        acc += a.x * b.x + a.y * b.y + a.z * b.z + a.w * b.w;
    }
#pragma unroll 8
    for (int q = 0; q < 32; q++) {
        float4 a = zp[q], b = w2[q];
        acc += a.x * b.x + a.y * b.y + a.z * b.z + a.w * b.w;
    }
    out[(size_t)i * 10 + c] = acc;
}

extern "C" void kernel_launch(void* const* d_in, const int* in_sizes, int n_in,
                              void* d_out, int out_size, void* d_ws, size_t ws_size,
                              hipStream_t stream) {
    const float* x   = (const float*)d_in[0];
    const int*   ei  = (const int*)d_in[1];
    const float* W1l = (const float*)d_in[2];
    const float* b1l = (const float*)d_in[3];
    const float* W1r = (const float*)d_in[4];
    const float* W2l = (const float*)d_in[5];
    const float* b2l = (const float*)d_in[6];
    const float* W2r = (const float*)d_in[7];
    const float* aux = (const float*)d_in[8];
    const float* Wc  = (const float*)d_in[9];
    const float* bc  = (const float*)d_in[10];
    float* out = (float*)d_out;

    const int N = in_sizes[0] / D;
    const int E = in_sizes[1] / 2;
    const int* srcArr = ei;
    const int* dstArr = ei + E;

    // int workspace (CSR)
    int* ip = (int*)d_ws;
    int* degi    = ip; ip += N;
    int* cursor  = ip; ip += N;        // degi+cursor contiguous -> one memset
    int* rowptr  = ip; ip += N + 1;
    int* csr_src = ip; ip += E;
    ip += (4 - ((uintptr_t)ip & 3));   // stay aligned (already is; harmless)

    float* p = (float*)ip;
    float* invdeg = p; p += N;
    float* sbuf   = p; p += N;
    float* wbuf   = p; p += N;
    float* M      = p; p += KTERMS * D;
    float* mden   = p; p += KTERMS;
    float* WT     = p; p += 4 * D * D;
    float* agg    = p; p += (size_t)N * D;
    float* h1     = p; p += (size_t)N * D;
    float* h2     = p; p += (size_t)N * D;
    float* zb     = p; p += (size_t)N * D;

    // zero: degi+cursor (ints), M+mden (floats, contiguous)
    hipMemsetAsync(degi, 0, (size_t)(2 * N) * sizeof(int), stream);
    hipMemsetAsync(M, 0, (size_t)(KTERMS * D + KTERMS) * sizeof(float), stream);

    transpose_w<<<64, 256, 0, stream>>>(W1l, WT + 0 * D * D);
    transpose_w<<<64, 256, 0, stream>>>(W1r, WT + 1 * D * D);
    transpose_w<<<64, 256, 0, stream>>>(W2l, WT + 2 * D * D);
    transpose_w<<<64, 256, 0, stream>>>(W2r, WT + 3 * D * D);

    // build CSR (sorted by dst)
    degi_kernel<<<(E + 255) / 256, 256, 0, stream>>>(dstArr, degi, E);
    invdeg_kernel<<<(N + 255) / 256, 256, 0, stream>>>(degi, invdeg, N);
    scan_kernel<<<1, 1024, 0, stream>>>(degi, rowptr, N);
    fill_kernel<<<(E + 255) / 256, 256, 0, stream>>>(srcArr, dstArr, rowptr, cursor, csr_src, E);

    // layer 1
    gather_kernel<<<(N + 3) / 4, 256, 0, stream>>>(x, rowptr, csr_src, invdeg, agg, N);
    sage_kernel<<<N / 16, 256, 0, stream>>>(agg, x, WT + 0 * D * D, WT + 1 * D * D, b1l, h1, 1);
    // layer 2
    gather_kernel<<<(N + 3) / 4, 256, 0, stream>>>(h1, rowptr, csr_src, invdeg, agg, N);
    sage_kernel<<<N / 16, 256, 0, stream>>>(agg, h1, WT + 2 * D * D, WT + 3 * D * D, b2l, h2, 0);

    // kernel aggregate via Taylor moment expansion
    score_kernel<<<(N + 3) / 4, 256, 0, stream>>>(h2, aux, sbuf, wbuf, N);
    moments_kernel<<<N / 64, 128, 0, stream>>>(h2, sbuf, wbuf, M, mden, N);
    zcalc_kernel<<<N / 16, 128, 0, stream>>>(M, mden, sbuf, zb, N);

    // classifier
    cls_kernel<<<(N * 16) / 256, 256, 0, stream>>>(h2, zb, Wc, bc, out, N);
}

// Round 5
// 221.712 us; speedup vs baseline: 3.1993x; 1.5669x over previous
//
#include <hip/hip_runtime.h>
#include <hip/hip_bf16.h>

#define D 128
#define KTERMS 16

typedef __attribute__((ext_vector_type(8))) short bf16x8;
typedef __attribute__((ext_vector_type(4))) float f32x4;

__device__ inline short rne_bf16(float f) {
    union { float f; unsigned u; } v; v.f = f;
    unsigned r = (v.u + 0x7fffu + ((v.u >> 16) & 1u)) >> 16;
    return (short)r;
}
__device__ inline float bf16_to_f(unsigned s) {
    union { unsigned u; float f; } v; v.u = s << 16;
    return v.f;
}

// ---------- build bf16 concat weights: Bc[layer][c][k] = k<128 ? Wl[c][k] : Wr[c][k-128] ----------
__global__ __launch_bounds__(256) void bcat_kernel(const float* __restrict__ W1l,
                                                   const float* __restrict__ W1r,
                                                   const float* __restrict__ W2l,
                                                   const float* __restrict__ W2r,
                                                   short* __restrict__ Bc1,
                                                   short* __restrict__ Bc2) {
    int idx = blockIdx.x * 256 + threadIdx.x;   // 2*128*256 = 65536 total
    int layer = idx >> 15;
    int rem = idx & 32767;
    int c = rem >> 8, k = rem & 255;
    const float* Wl = layer ? W2l : W1l;
    const float* Wr = layer ? W2r : W1r;
    float v = (k < 128) ? Wl[c * 128 + k] : Wr[c * 128 + (k - 128)];
    short* Bc = layer ? Bc2 : Bc1;
    Bc[c * 256 + k] = rne_bf16(v);
}

// ---------- f32 -> bf16 matrix convert (8 elems/thread) ----------
__global__ __launch_bounds__(256) void cvt_kernel(const float* __restrict__ in,
                                                  short* __restrict__ outb, int total) {
    int base = (blockIdx.x * 256 + threadIdx.x) * 8;
    if (base >= total) return;
    const float4 a = *reinterpret_cast<const float4*>(&in[base]);
    const float4 b = *reinterpret_cast<const float4*>(&in[base + 4]);
    uint4 o;
    o.x = (unsigned)(unsigned short)rne_bf16(a.x) | ((unsigned)(unsigned short)rne_bf16(a.y) << 16);
    o.y = (unsigned)(unsigned short)rne_bf16(a.z) | ((unsigned)(unsigned short)rne_bf16(a.w) << 16);
    o.z = (unsigned)(unsigned short)rne_bf16(b.x) | ((unsigned)(unsigned short)rne_bf16(b.y) << 16);
    o.w = (unsigned)(unsigned short)rne_bf16(b.z) | ((unsigned)(unsigned short)rne_bf16(b.w) << 16);
    *reinterpret_cast<uint4*>(&outb[base]) = o;
}

// ---------- int degree histogram ----------
__global__ __launch_bounds__(256) void degi_kernel(const int* __restrict__ dst,
                                                   int* __restrict__ degi, int E) {
    int e = blockIdx.x * 256 + threadIdx.x;
    if (e < E) atomicAdd(&degi[dst[e]], 1);
}

__global__ __launch_bounds__(256) void invdeg_kernel(const int* __restrict__ degi,
                                                     float* __restrict__ invdeg, int N) {
    int i = blockIdx.x * 256 + threadIdx.x;
    if (i < N) invdeg[i] = 1.0f / fmaxf((float)degi[i], 1.0f);
}

// ---------- exclusive prefix scan of degi -> rowptr (N=16384, 1 block of 1024) ----------
__global__ __launch_bounds__(1024) void scan_kernel(const int* __restrict__ degi,
                                                    int* __restrict__ rowptr, int N) {
    __shared__ int part[1024];
    int tid = threadIdx.x;
    int base = tid * 16;
    int loc[16];
    int s = 0;
#pragma unroll
    for (int i = 0; i < 16; i++) { loc[i] = s; s += degi[base + i]; }
    part[tid] = s;
    __syncthreads();
    for (int off = 1; off < 1024; off <<= 1) {
        int t = (tid >= off) ? part[tid - off] : 0;
        __syncthreads();
        if (tid >= off) part[tid] += t;
        __syncthreads();
    }
    int prefix = part[tid] - s;  // exclusive
#pragma unroll
    for (int i = 0; i < 16; i++) rowptr[base + i] = prefix + loc[i];
    if (tid == 1023) rowptr[N] = prefix + s;
}

// ---------- CSR fill ----------
__global__ __launch_bounds__(256) void fill_kernel(const int* __restrict__ src,
                                                   const int* __restrict__ dst,
                                                   const int* __restrict__ rowptr,
                                                   int* __restrict__ cursor,
                                                   int* __restrict__ csr_src, int E) {
    int e = blockIdx.x * 256 + threadIdx.x;
    if (e < E) {
        int d = dst[e];
        int pos = atomicAdd(&cursor[d], 1);
        csr_src[rowptr[d] + pos] = src[e];
    }
}

// ---------- gather-mean over bf16 rows: aggb[i] = bf16(mean_{j in N(i)} xin[j]) ----------
__global__ __launch_bounds__(256) void gatherb_kernel(const short* __restrict__ xin,
                                                      const int* __restrict__ rowptr,
                                                      const int* __restrict__ csr_src,
                                                      const float* __restrict__ invdeg,
                                                      short* __restrict__ aggb, int N) {
    int wave = threadIdx.x >> 6, lane = threadIdx.x & 63;
    int node = blockIdx.x * 4 + wave;
    if (node >= N) return;
    int beg = rowptr[node], end = rowptr[node + 1];
    float ax = 0.0f, ay = 0.0f;
    for (int j = beg; j < end; j++) {
        int s = csr_src[j];
        unsigned v = *reinterpret_cast<const unsigned*>(&xin[(size_t)s * D + lane * 2]);
        ax += bf16_to_f(v & 0xffffu);
        ay += bf16_to_f(v >> 16);
    }
    float inv = invdeg[node];
    unsigned o = (unsigned)(unsigned short)rne_bf16(ax * inv) |
                 ((unsigned)(unsigned short)rne_bf16(ay * inv) << 16);
    *reinterpret_cast<unsigned*>(&aggb[(size_t)node * D + lane * 2]) = o;
}

// ---------- MFMA SAGE: out = [relu]([Aagg|Aroot] @ Bc^T + bias) ----------
// A matrices [N x 128] bf16; Bc [128 cols x 256 k] bf16 (= [Wl|Wr] row-major).
// Per block: 4 waves (2 row x 2 col), 32 rows x 128 cols. Grid = N/32.
__global__ __launch_bounds__(256) void sage_mfma_kernel(const short* __restrict__ Aagg,
                                                        const short* __restrict__ Aroot,
                                                        const short* __restrict__ Bc,
                                                        const float* __restrict__ bias,
                                                        float* __restrict__ outf,
                                                        short* __restrict__ outb,
                                                        int relu) {
    int lane = threadIdx.x & 63;
    int wid = threadIdx.x >> 6;
    int row0 = blockIdx.x * 32 + (wid & 1) * 16;
    int colbase = (wid >> 1) * 64;

    int arow = row0 + (lane & 15);
    int koff = (lane >> 4) * 8;

    f32x4 acc[4];
#pragma unroll
    for (int t = 0; t < 4; t++) acc[t] = (f32x4){0.0f, 0.0f, 0.0f, 0.0f};

#pragma unroll
    for (int kc = 0; kc < 8; kc++) {
        const short* Asrc = (kc < 4) ? Aagg : Aroot;
        int k = (kc & 3) * 32 + koff;
        bf16x8 a = *reinterpret_cast<const bf16x8*>(&Asrc[(size_t)arow * D + k]);
#pragma unroll
        for (int t = 0; t < 4; t++) {
            int col = colbase + t * 16 + (lane & 15);
            bf16x8 b = *reinterpret_cast<const bf16x8*>(&Bc[(size_t)col * 256 + kc * 32 + koff]);
            acc[t] = __builtin_amdgcn_mfma_f32_16x16x32_bf16(a, b, acc[t], 0, 0, 0);
        }
    }

    int rbase = row0 + (lane >> 4) * 4;
#pragma unroll
    for (int t = 0; t < 4; t++) {
        int col = colbase + t * 16 + (lane & 15);
        float bv = bias[col];
#pragma unroll
        for (int r = 0; r < 4; r++) {
            float v = acc[t][r] + bv;
            if (relu) v = fmaxf(v, 0.0f);
            if (outf) outf[(size_t)(rbase + r) * D + col] = v;
            else outb[(size_t)(rbase + r) * D + col] = rne_bf16(v);
        }
    }
}

// ---------- per-node cosine score vs aux, and w = exp(-s^2) ----------
__global__ __launch_bounds__(256) void score_kernel(const float* __restrict__ h,
                                                    const float* __restrict__ aux,
                                                    float* __restrict__ sbuf,
                                                    float* __restrict__ wbuf, int N) {
    int wave = threadIdx.x >> 6, lane = threadIdx.x & 63;
    int node = blockIdx.x * 4 + wave;
    if (node >= N) return;
    float2 hv = *reinterpret_cast<const float2*>(&h[(size_t)node * D + lane * 2]);
    float2 av = *reinterpret_cast<const float2*>(&aux[lane * 2]);
    float dot = hv.x * av.x + hv.y * av.y;
    float nh = hv.x * hv.x + hv.y * hv.y;
    float na = av.x * av.x + av.y * av.y;
    for (int m = 1; m < 64; m <<= 1) {
        dot += __shfl_xor(dot, m);
        nh += __shfl_xor(nh, m);
        na += __shfl_xor(na, m);
    }
    if (lane == 0) {
        float hn = fmaxf(sqrtf(nh), 1e-8f);
        float an = fmaxf(sqrtf(na), 1e-8f);
        float sc = dot / (hn * an);
        sbuf[node] = sc;
        wbuf[node] = expf(-sc * sc);
    }
}

// ---------- moments ----------
__global__ __launch_bounds__(128) void moments_kernel(const float* __restrict__ h,
                                                      const float* __restrict__ sbuf,
                                                      const float* __restrict__ wbuf,
                                                      float* __restrict__ M,
                                                      float* __restrict__ mden, int N) {
    int tid = threadIdx.x;
    int j0 = blockIdx.x * 64;
    float acc[KTERMS], macc[KTERMS];
#pragma unroll
    for (int k = 0; k < KTERMS; k++) { acc[k] = 0.0f; macc[k] = 0.0f; }
    for (int j = j0; j < j0 + 64; j++) {
        float sj = sbuf[j];
        float wj = wbuf[j];
        float hv = h[(size_t)j * D + tid];
        float coef = wj;
#pragma unroll
        for (int k = 0; k < KTERMS; k++) {
            acc[k] += coef * hv;
            macc[k] += coef;
            coef *= sj;
        }
    }
#pragma unroll
    for (int k = 0; k < KTERMS; k++) atomicAdd(&M[k * D + tid], acc[k]);
    if (tid == 0) {
#pragma unroll
        for (int k = 0; k < KTERMS; k++) atomicAdd(&mden[k], macc[k]);
    }
}

// ---------- z ----------
__global__ __launch_bounds__(128) void zcalc_kernel(const float* __restrict__ M,
                                                    const float* __restrict__ mden,
                                                    const float* __restrict__ sbuf,
                                                    float* __restrict__ z, int N) {
    const float A[KTERMS] = {1.0f, 2.0f, 2.0f, 1.3333334f, 0.6666667f, 0.26666668f,
                             0.08888889f, 0.025396826f, 0.0063492064f, 0.0014109347f,
                             2.8218695e-4f, 5.1306718e-5f, 8.5511196e-6f, 1.3155569e-6f,
                             1.8793670e-7f, 2.5058226e-8f};
    __shared__ float Ml[KTERMS * D];
    __shared__ float ml[KTERMS];
    int tid = threadIdx.x;
#pragma unroll
    for (int k = 0; k < KTERMS; k++) Ml[k * D + tid] = M[k * D + tid];
    if (tid < KTERMS) ml[tid] = mden[tid];
    __syncthreads();
    int n0 = blockIdx.x * 16;
    for (int n = n0; n < n0 + 16; n++) {
        float si = sbuf[n];
        float num = 0.0f, den = 0.0f, p = 1.0f;
#pragma unroll
        for (int k = 0; k < KTERMS; k++) {
            float ck = A[k] * p;
            num += ck * Ml[k * D + tid];
            den += ck * ml[k];
            p *= si;
        }
        z[(size_t)n * D + tid] = num / den;
    }
}

// ---------- classifier ----------
__global__ __launch_bounds__(256) void cls_kernel(const float* __restrict__ h,
                                                  const float* __restrict__ z,
                                                  const float* __restrict__ Wc,
                                                  const float* __restrict__ bc,
                                                  float* __restrict__ out, int N) {
    int idx = blockIdx.x * 256 + threadIdx.x;
    int i = idx >> 4, c = idx & 15;
    if (i >= N || c >= 10) return;
    float acc = bc[c];
    const float4* hp = reinterpret_cast<const float4*>(&h[(size_t)i * D]);
    const float4* zp = reinterpret_cast<const float4*>(&z[(size_t)i * D]);
    const float4* w1 = reinterpret_cast<const float4*>(&Wc[(size_t)c * 256]);
    const float4* w2 = reinterpret_cast<const float4*>(&Wc[(size_t)c * 256 + 128]);
#pragma unroll 8
    for (int q = 0; q < 32; q++) {
        float4 a = hp[q], b = w1[q];
        acc += a.x * b.x + a.y * b.y + a.z * b.z + a.w * b.w;
    }
#pragma unroll 8
    for (int q = 0; q < 32; q++) {
        float4 a = zp[q], b = w2[q];
        acc += a.x * b.x + a.y * b.y + a.z * b.z + a.w * b.w;
    }
    out[(size_t)i * 10 + c] = acc;
}

extern "C" void kernel_launch(void* const* d_in, const int* in_sizes, int n_in,
                              void* d_out, int out_size, void* d_ws, size_t ws_size,
                              hipStream_t stream) {
    const float* x   = (const float*)d_in[0];
    const int*   ei  = (const int*)d_in[1];
    const float* W1l = (const float*)d_in[2];
    const float* b1l = (const float*)d_in[3];
    const float* W1r = (const float*)d_in[4];
    const float* W2l = (const float*)d_in[5];
    const float* b2l = (const float*)d_in[6];
    const float* W2r = (const float*)d_in[7];
    const float* aux = (const float*)d_in[8];
    const float* Wc  = (const float*)d_in[9];
    const float* bc  = (const float*)d_in[10];
    float* out = (float*)d_out;

    const int N = in_sizes[0] / D;
    const int E = in_sizes[1] / 2;
    const int* srcArr = ei;
    const int* dstArr = ei + E;
    const size_t ND = (size_t)N * D;

    // ---- workspace carve-up ----
    // ints (CSR)
    int* ip = (int*)d_ws;
    int* degi    = ip; ip += N;
    int* cursor  = ip; ip += N;
    int* rowptr  = ip; ip += N + 1;
    int* csr_src = ip; ip += E;
    // align to 16B
    uintptr_t up = ((uintptr_t)ip + 15) & ~(uintptr_t)15;
    // bf16 buffers
    short* sp = (short*)up;
    short* xb   = sp; sp += ND;
    short* aggb = sp; sp += ND;
    short* h1b  = sp; sp += ND;
    short* Bc1  = sp; sp += 128 * 256;
    short* Bc2  = sp; sp += 128 * 256;
    // f32 buffers
    up = ((uintptr_t)sp + 15) & ~(uintptr_t)15;
    float* p = (float*)up;
    float* invdeg = p; p += N;
    float* sbuf   = p; p += N;
    float* wbuf   = p; p += N;
    float* M      = p; p += KTERMS * D;
    float* mden   = p; p += KTERMS;
    float* h2     = p; p += ND;
    float* zb     = p; p += ND;

    hipMemsetAsync(degi, 0, (size_t)(2 * N) * sizeof(int), stream);
    hipMemsetAsync(M, 0, (size_t)(KTERMS * D + KTERMS) * sizeof(float), stream);

    // weight concat + input convert
    bcat_kernel<<<256, 256, 0, stream>>>(W1l, W1r, W2l, W2r, Bc1, Bc2);
    cvt_kernel<<<(int)(ND / 8 / 256), 256, 0, stream>>>(x, xb, (int)ND);

    // build CSR (sorted by dst)
    degi_kernel<<<(E + 255) / 256, 256, 0, stream>>>(dstArr, degi, E);
    invdeg_kernel<<<(N + 255) / 256, 256, 0, stream>>>(degi, invdeg, N);
    scan_kernel<<<1, 1024, 0, stream>>>(degi, rowptr, N);
    fill_kernel<<<(E + 255) / 256, 256, 0, stream>>>(srcArr, dstArr, rowptr, cursor, csr_src, E);

    // layer 1: h1b = relu([gather(xb)|xb] @ Bc1^T + b1l)   (bf16 out)
    gatherb_kernel<<<(N + 3) / 4, 256, 0, stream>>>(xb, rowptr, csr_src, invdeg, aggb, N);
    sage_mfma_kernel<<<N / 32, 256, 0, stream>>>(aggb, xb, Bc1, b1l, nullptr, h1b, 1);

    // layer 2: h2 = [gather(h1b)|h1b] @ Bc2^T + b2l        (f32 out)
    gatherb_kernel<<<(N + 3) / 4, 256, 0, stream>>>(h1b, rowptr, csr_src, invdeg, aggb, N);
    sage_mfma_kernel<<<N / 32, 256, 0, stream>>>(aggb, h1b, Bc2, b2l, h2, nullptr, 0);

    // kernel aggregate via Taylor moment expansion
    score_kernel<<<(N + 3) / 4, 256, 0, stream>>>(h2, aux, sbuf, wbuf, N);
    moments_kernel<<<N / 64, 128, 0, stream>>>(h2, sbuf, wbuf, M, mden, N);
    zcalc_kernel<<<N / 16, 128, 0, stream>>>(M, mden, sbuf, zb, N);

    // classifier
    cls_kernel<<<(N * 16) / 256, 256, 0, stream>>>(h2, zb, Wc, bc, out, N);
}

// Round 6
// 186.446 us; speedup vs baseline: 3.8045x; 1.1892x over previous
//
#include <hip/hip_runtime.h>
#include <hip/hip_bf16.h>

#define D 128
#define KTERMS 16

typedef __attribute__((ext_vector_type(8))) short bf16x8;
typedef __attribute__((ext_vector_type(4))) float f32x4;

__device__ inline short rne_bf16(float f) {
    union { float f; unsigned u; } v; v.f = f;
    unsigned r = (v.u + 0x7fffu + ((v.u >> 16) & 1u)) >> 16;
    return (short)r;
}
__device__ inline float bf16_to_f(unsigned s) {
    union { unsigned u; float f; } v; v.u = s << 16;
    return v.f;
}

// ---------- build bf16 concat weights: Bc[layer][c][k] = k<128 ? Wl[c][k] : Wr[c][k-128] ----------
__global__ __launch_bounds__(256) void bcat_kernel(const float* __restrict__ W1l,
                                                   const float* __restrict__ W1r,
                                                   const float* __restrict__ W2l,
                                                   const float* __restrict__ W2r,
                                                   short* __restrict__ Bc1,
                                                   short* __restrict__ Bc2) {
    int idx = blockIdx.x * 256 + threadIdx.x;   // 2*128*256 = 65536 total
    int layer = idx >> 15;
    int rem = idx & 32767;
    int c = rem >> 8, k = rem & 255;
    const float* Wl = layer ? W2l : W1l;
    const float* Wr = layer ? W2r : W1r;
    float v = (k < 128) ? Wl[c * 128 + k] : Wr[c * 128 + (k - 128)];
    short* Bc = layer ? Bc2 : Bc1;
    Bc[c * 256 + k] = rne_bf16(v);
}

// ---------- f32 -> bf16 matrix convert (8 elems/thread) ----------
__global__ __launch_bounds__(256) void cvt_kernel(const float* __restrict__ in,
                                                  short* __restrict__ outb, int total) {
    int base = (blockIdx.x * 256 + threadIdx.x) * 8;
    if (base >= total) return;
    const float4 a = *reinterpret_cast<const float4*>(&in[base]);
    const float4 b = *reinterpret_cast<const float4*>(&in[base + 4]);
    uint4 o;
    o.x = (unsigned)(unsigned short)rne_bf16(a.x) | ((unsigned)(unsigned short)rne_bf16(a.y) << 16);
    o.y = (unsigned)(unsigned short)rne_bf16(a.z) | ((unsigned)(unsigned short)rne_bf16(a.w) << 16);
    o.z = (unsigned)(unsigned short)rne_bf16(b.x) | ((unsigned)(unsigned short)rne_bf16(b.y) << 16);
    o.w = (unsigned)(unsigned short)rne_bf16(b.z) | ((unsigned)(unsigned short)rne_bf16(b.w) << 16);
    *reinterpret_cast<uint4*>(&outb[base]) = o;
}

// ---------- int degree histogram ----------
__global__ __launch_bounds__(256) void degi_kernel(const int* __restrict__ dst,
                                                   int* __restrict__ degi, int E) {
    int e = blockIdx.x * 256 + threadIdx.x;
    if (e < E) atomicAdd(&degi[dst[e]], 1);
}

__global__ __launch_bounds__(256) void invdeg_kernel(const int* __restrict__ degi,
                                                     float* __restrict__ invdeg, int N) {
    int i = blockIdx.x * 256 + threadIdx.x;
    if (i < N) invdeg[i] = 1.0f / fmaxf((float)degi[i], 1.0f);
}

// ---------- exclusive prefix scan of degi -> rowptr (N=16384, 1 block of 1024) ----------
__global__ __launch_bounds__(1024) void scan_kernel(const int* __restrict__ degi,
                                                    int* __restrict__ rowptr, int N) {
    __shared__ int part[1024];
    int tid = threadIdx.x;
    int base = tid * 16;
    int loc[16];
    int s = 0;
#pragma unroll
    for (int i = 0; i < 16; i++) { loc[i] = s; s += degi[base + i]; }
    part[tid] = s;
    __syncthreads();
    for (int off = 1; off < 1024; off <<= 1) {
        int t = (tid >= off) ? part[tid - off] : 0;
        __syncthreads();
        if (tid >= off) part[tid] += t;
        __syncthreads();
    }
    int prefix = part[tid] - s;  // exclusive
#pragma unroll
    for (int i = 0; i < 16; i++) rowptr[base + i] = prefix + loc[i];
    if (tid == 1023) rowptr[N] = prefix + s;
}

// ---------- CSR fill ----------
__global__ __launch_bounds__(256) void fill_kernel(const int* __restrict__ src,
                                                   const int* __restrict__ dst,
                                                   const int* __restrict__ rowptr,
                                                   int* __restrict__ cursor,
                                                   int* __restrict__ csr_src, int E) {
    int e = blockIdx.x * 256 + threadIdx.x;
    if (e < E) {
        int d = dst[e];
        int pos = atomicAdd(&cursor[d], 1);
        csr_src[rowptr[d] + pos] = src[e];
    }
}

// ---------- gather-mean over bf16 rows: aggb[i] = bf16(mean_{j in N(i)} xin[j]) ----------
__global__ __launch_bounds__(256) void gatherb_kernel(const short* __restrict__ xin,
                                                      const int* __restrict__ rowptr,
                                                      const int* __restrict__ csr_src,
                                                      const float* __restrict__ invdeg,
                                                      short* __restrict__ aggb, int N) {
    int wave = threadIdx.x >> 6, lane = threadIdx.x & 63;
    int node = blockIdx.x * 4 + wave;
    if (node >= N) return;
    int beg = rowptr[node], end = rowptr[node + 1];
    float ax = 0.0f, ay = 0.0f;
    for (int j = beg; j < end; j++) {
        int s = csr_src[j];
        unsigned v = *reinterpret_cast<const unsigned*>(&xin[(size_t)s * D + lane * 2]);
        ax += bf16_to_f(v & 0xffffu);
        ay += bf16_to_f(v >> 16);
    }
    float inv = invdeg[node];
    unsigned o = (unsigned)(unsigned short)rne_bf16(ax * inv) |
                 ((unsigned)(unsigned short)rne_bf16(ay * inv) << 16);
    *reinterpret_cast<unsigned*>(&aggb[(size_t)node * D + lane * 2]) = o;
}

// ---------- MFMA SAGE: out = [relu]([Aagg|Aroot] @ Bc^T + bias) ----------
__global__ __launch_bounds__(256) void sage_mfma_kernel(const short* __restrict__ Aagg,
                                                        const short* __restrict__ Aroot,
                                                        const short* __restrict__ Bc,
                                                        const float* __restrict__ bias,
                                                        float* __restrict__ outf,
                                                        short* __restrict__ outb,
                                                        int relu) {
    int lane = threadIdx.x & 63;
    int wid = threadIdx.x >> 6;
    int row0 = blockIdx.x * 32 + (wid & 1) * 16;
    int colbase = (wid >> 1) * 64;

    int arow = row0 + (lane & 15);
    int koff = (lane >> 4) * 8;

    f32x4 acc[4];
#pragma unroll
    for (int t = 0; t < 4; t++) acc[t] = (f32x4){0.0f, 0.0f, 0.0f, 0.0f};

#pragma unroll
    for (int kc = 0; kc < 8; kc++) {
        const short* Asrc = (kc < 4) ? Aagg : Aroot;
        int k = (kc & 3) * 32 + koff;
        bf16x8 a = *reinterpret_cast<const bf16x8*>(&Asrc[(size_t)arow * D + k]);
#pragma unroll
        for (int t = 0; t < 4; t++) {
            int col = colbase + t * 16 + (lane & 15);
            bf16x8 b = *reinterpret_cast<const bf16x8*>(&Bc[(size_t)col * 256 + kc * 32 + koff]);
            acc[t] = __builtin_amdgcn_mfma_f32_16x16x32_bf16(a, b, acc[t], 0, 0, 0);
        }
    }

    int rbase = row0 + (lane >> 4) * 4;
#pragma unroll
    for (int t = 0; t < 4; t++) {
        int col = colbase + t * 16 + (lane & 15);
        float bv = bias[col];
#pragma unroll
        for (int r = 0; r < 4; r++) {
            float v = acc[t][r] + bv;
            if (relu) v = fmaxf(v, 0.0f);
            if (outf) outf[(size_t)(rbase + r) * D + col] = v;
            else outb[(size_t)(rbase + r) * D + col] = rne_bf16(v);
        }
    }
}

// ---------- per-node cosine score vs aux, and w = exp(-s^2) ----------
__global__ __launch_bounds__(256) void score_kernel(const float* __restrict__ h,
                                                    const float* __restrict__ aux,
                                                    float* __restrict__ sbuf,
                                                    float* __restrict__ wbuf, int N) {
    int wave = threadIdx.x >> 6, lane = threadIdx.x & 63;
    int node = blockIdx.x * 4 + wave;
    if (node >= N) return;
    float2 hv = *reinterpret_cast<const float2*>(&h[(size_t)node * D + lane * 2]);
    float2 av = *reinterpret_cast<const float2*>(&aux[lane * 2]);
    float dot = hv.x * av.x + hv.y * av.y;
    float nh = hv.x * hv.x + hv.y * hv.y;
    float na = av.x * av.x + av.y * av.y;
    for (int m = 1; m < 64; m <<= 1) {
        dot += __shfl_xor(dot, m);
        nh += __shfl_xor(nh, m);
        na += __shfl_xor(na, m);
    }
    if (lane == 0) {
        float hn = fmaxf(sqrtf(nh), 1e-8f);
        float an = fmaxf(sqrtf(na), 1e-8f);
        float sc = dot / (hn * an);
        sbuf[node] = sc;
        wbuf[node] = expf(-sc * sc);
    }
}

// ---------- moments v2: 512 threads, 8 waves x 8 rows, LDS cross-wave reduce ----------
__global__ __launch_bounds__(512) void moments_kernel(const float* __restrict__ h,
                                                      const float* __restrict__ sbuf,
                                                      const float* __restrict__ wbuf,
                                                      float* __restrict__ M,
                                                      float* __restrict__ mden, int N) {
    __shared__ float lds[8 * KTERMS * D];     // 64 KB
    __shared__ float ldsm[8 * KTERMS];
    int tid = threadIdx.x;
    int w = tid >> 6, lane = tid & 63;
    int j0 = blockIdx.x * 64 + w * 8;

    float2 acc[KTERMS];
    float macc[KTERMS];
#pragma unroll
    for (int k = 0; k < KTERMS; k++) { acc[k] = make_float2(0.0f, 0.0f); macc[k] = 0.0f; }

    for (int j = j0; j < j0 + 8; j++) {
        float sj = sbuf[j];
        float wj = wbuf[j];
        float2 hv = *reinterpret_cast<const float2*>(&h[(size_t)j * D + lane * 2]);
        float coef = wj;
#pragma unroll
        for (int k = 0; k < KTERMS; k++) {
            acc[k].x += coef * hv.x;
            acc[k].y += coef * hv.y;
            macc[k] += coef;
            coef *= sj;
        }
    }

#pragma unroll
    for (int k = 0; k < KTERMS; k++) {
        lds[(w * KTERMS + k) * D + lane * 2]     = acc[k].x;
        lds[(w * KTERMS + k) * D + lane * 2 + 1] = acc[k].y;
    }
    if (lane == 0) {
#pragma unroll
        for (int k = 0; k < KTERMS; k++) ldsm[w * KTERMS + k] = macc[k];
    }
    __syncthreads();

    for (int e = tid; e < KTERMS * D; e += 512) {
        float s = 0.0f;
#pragma unroll
        for (int ww = 0; ww < 8; ww++) s += lds[ww * KTERMS * D + e];
        atomicAdd(&M[e], s);
    }
    if (tid < KTERMS) {
        float s = 0.0f;
#pragma unroll
        for (int ww = 0; ww < 8; ww++) s += ldsm[ww * KTERMS + tid];
        atomicAdd(&mden[tid], s);
    }
}

// ---------- z ----------
__global__ __launch_bounds__(128) void zcalc_kernel(const float* __restrict__ M,
                                                    const float* __restrict__ mden,
                                                    const float* __restrict__ sbuf,
                                                    float* __restrict__ z, int N) {
    const float A[KTERMS] = {1.0f, 2.0f, 2.0f, 1.3333334f, 0.6666667f, 0.26666668f,
                             0.08888889f, 0.025396826f, 0.0063492064f, 0.0014109347f,
                             2.8218695e-4f, 5.1306718e-5f, 8.5511196e-6f, 1.3155569e-6f,
                             1.8793670e-7f, 2.5058226e-8f};
    __shared__ float Ml[KTERMS * D];
    __shared__ float ml[KTERMS];
    int tid = threadIdx.x;
#pragma unroll
    for (int k = 0; k < KTERMS; k++) Ml[k * D + tid] = M[k * D + tid];
    if (tid < KTERMS) ml[tid] = mden[tid];
    __syncthreads();
    int n0 = blockIdx.x * 16;
    for (int n = n0; n < n0 + 16; n++) {
        float si = sbuf[n];
        float num = 0.0f, den = 0.0f, p = 1.0f;
#pragma unroll
        for (int k = 0; k < KTERMS; k++) {
            float ck = A[k] * p;
            num += ck * Ml[k * D + tid];
            den += ck * ml[k];
            p *= si;
        }
        z[(size_t)n * D + tid] = num / den;
    }
}

// ---------- classifier ----------
__global__ __launch_bounds__(256) void cls_kernel(const float* __restrict__ h,
                                                  const float* __restrict__ z,
                                                  const float* __restrict__ Wc,
                                                  const float* __restrict__ bc,
                                                  float* __restrict__ out, int N) {
    int idx = blockIdx.x * 256 + threadIdx.x;
    int i = idx >> 4, c = idx & 15;
    if (i >= N || c >= 10) return;
    float acc = bc[c];
    const float4* hp = reinterpret_cast<const float4*>(&h[(size_t)i * D]);
    const float4* zp = reinterpret_cast<const float4*>(&z[(size_t)i * D]);
    const float4* w1 = reinterpret_cast<const float4*>(&Wc[(size_t)c * 256]);
    const float4* w2 = reinterpret_cast<const float4*>(&Wc[(size_t)c * 256 + 128]);
#pragma unroll 8
    for (int q = 0; q < 32; q++) {
        float4 a = hp[q], b = w1[q];
        acc += a.x * b.x + a.y * b.y + a.z * b.z + a.w * b.w;
    }
#pragma unroll 8
    for (int q = 0; q < 32; q++) {
        float4 a = zp[q], b = w2[q];
        acc += a.x * b.x + a.y * b.y + a.z * b.z + a.w * b.w;
    }
    out[(size_t)i * 10 + c] = acc;
}

extern "C" void kernel_launch(void* const* d_in, const int* in_sizes, int n_in,
                              void* d_out, int out_size, void* d_ws, size_t ws_size,
                              hipStream_t stream) {
    const float* x   = (const float*)d_in[0];
    const int*   ei  = (const int*)d_in[1];
    const float* W1l = (const float*)d_in[2];
    const float* b1l = (const float*)d_in[3];
    const float* W1r = (const float*)d_in[4];
    const float* W2l = (const float*)d_in[5];
    const float* b2l = (const float*)d_in[6];
    const float* W2r = (const float*)d_in[7];
    const float* aux = (const float*)d_in[8];
    const float* Wc  = (const float*)d_in[9];
    const float* bc  = (const float*)d_in[10];
    float* out = (float*)d_out;

    const int N = in_sizes[0] / D;
    const int E = in_sizes[1] / 2;
    const int* srcArr = ei;
    const int* dstArr = ei + E;
    const size_t ND = (size_t)N * D;

    // ---- workspace carve-up ----
    int* ip = (int*)d_ws;
    int* degi    = ip; ip += N;
    int* cursor  = ip; ip += N;
    int* rowptr  = ip; ip += N + 1;
    int* csr_src = ip; ip += E;
    uintptr_t up = ((uintptr_t)ip + 15) & ~(uintptr_t)15;
    short* sp = (short*)up;
    short* xb   = sp; sp += ND;
    short* aggb = sp; sp += ND;
    short* h1b  = sp; sp += ND;
    short* Bc1  = sp; sp += 128 * 256;
    short* Bc2  = sp; sp += 128 * 256;
    up = ((uintptr_t)sp + 15) & ~(uintptr_t)15;
    float* p = (float*)up;
    float* invdeg = p; p += N;
    float* sbuf   = p; p += N;
    float* wbuf   = p; p += N;
    float* M      = p; p += KTERMS * D;
    float* mden   = p; p += KTERMS;
    float* h2     = p; p += ND;
    float* zb     = p; p += ND;

    hipMemsetAsync(degi, 0, (size_t)(2 * N) * sizeof(int), stream);
    hipMemsetAsync(M, 0, (size_t)(KTERMS * D + KTERMS) * sizeof(float), stream);

    // weight concat + input convert
    bcat_kernel<<<256, 256, 0, stream>>>(W1l, W1r, W2l, W2r, Bc1, Bc2);
    cvt_kernel<<<(int)(ND / 8 / 256), 256, 0, stream>>>(x, xb, (int)ND);

    // build CSR (sorted by dst)
    degi_kernel<<<(E + 255) / 256, 256, 0, stream>>>(dstArr, degi, E);
    invdeg_kernel<<<(N + 255) / 256, 256, 0, stream>>>(degi, invdeg, N);
    scan_kernel<<<1, 1024, 0, stream>>>(degi, rowptr, N);
    fill_kernel<<<(E + 255) / 256, 256, 0, stream>>>(srcArr, dstArr, rowptr, cursor, csr_src, E);

    // layer 1: h1b = relu([gather(xb)|xb] @ Bc1^T + b1l)   (bf16 out)
    gatherb_kernel<<<(N + 3) / 4, 256, 0, stream>>>(xb, rowptr, csr_src, invdeg, aggb, N);
    sage_mfma_kernel<<<N / 32, 256, 0, stream>>>(aggb, xb, Bc1, b1l, nullptr, h1b, 1);

    // layer 2: h2 = [gather(h1b)|h1b] @ Bc2^T + b2l        (f32 out)
    gatherb_kernel<<<(N + 3) / 4, 256, 0, stream>>>(h1b, rowptr, csr_src, invdeg, aggb, N);
    sage_mfma_kernel<<<N / 32, 256, 0, stream>>>(aggb, h1b, Bc2, b2l, h2, nullptr, 0);

    // kernel aggregate via Taylor moment expansion
    score_kernel<<<(N + 3) / 4, 256, 0, stream>>>(h2, aux, sbuf, wbuf, N);
    moments_kernel<<<N / 64, 512, 0, stream>>>(h2, sbuf, wbuf, M, mden, N);
    zcalc_kernel<<<N / 16, 128, 0, stream>>>(M, mden, sbuf, zb, N);

    // classifier
    cls_kernel<<<(N * 16) / 256, 256, 0, stream>>>(h2, zb, Wc, bc, out, N);
}